// Round 13
// baseline (78.903 us; speedup 1.0000x reference)
//
#include <hip/hip_runtime.h>
#include <math.h>

#define CCH 256
#define HP2 68
#define WP2 68
#define PLANE 4624            // 68*68
#define NPIX 16384

typedef __attribute__((ext_vector_type(8))) short bf16x8;
typedef __attribute__((ext_vector_type(8))) unsigned short u16x8;
typedef __attribute__((ext_vector_type(4))) float f32x4;

__device__ __forceinline__ unsigned short f2bf(float f) {
    unsigned int u = __float_as_uint(f);
    unsigned int r = (u + 0x7fffu + ((u >> 16) & 1u)) >> 16;
    return (unsigned short)r;
}
__device__ __forceinline__ float bf2f(unsigned short h) {
    return __uint_as_float(((unsigned int)h) << 16);
}

// async global->LDS, 16B per lane; LDS dest is wave-uniform base + lane*16
__device__ __forceinline__ void gll16(const unsigned short* g, unsigned short* l) {
    __builtin_amdgcn_global_load_lds(
        (const __attribute__((address_space(1))) unsigned int*)g,
        (__attribute__((address_space(3))) unsigned int*)l,
        16, 0, 0);
}

// ---- workspace layout (bytes) ----
#define OFF_XNBF   0ull          // 16384*256 bf16 = 8,388,608  (reused as y_bf after stage2)
#define OFF_XPAD   8388608ull    // 4*16*4624*16 bf16 = 9,469,952  GROUP-PLANAR [n][g][68][68][16]
#define OFF_X1BF   17858560ull   // 16384*256 bf16 = 8,388,608
#define OFF_REC    26247168ull   // 16*16384 records x 64B = 16,777,216  [g][m][32 ushorts]
#define OFF_WTIN   43024384ull   // 256*256 bf16   = 131,072
#define OFF_WTOFF  43155456ull   // 288*256 bf16   = 147,456   (wtoff+wtmsk+pad contiguous = 512xK)
#define OFF_WTMSK  43302912ull   // 144*256 bf16   = 73,728
#define OFF_BPAD   43376640ull   // 80*256 bf16    = 40,960   (zero pad rows 432..511)
#define OFF_WTOUT  43417600ull   // 256*256 bf16   = 131,072
#define OFF_BOM    43548672ull   // 432 f32        = 1,728
#define OFF_DWT    43550400ull   // 9*256 bf16     = 4,608  (depthwise w, tap-major)
// end = 43,555,008 bytes

// prep: z<4 -> NCHW f32 -> NHWC bf16 (+ ring-zero xpad); z=4..7 -> weight transposes; z=8 -> misc
__global__ __launch_bounds__(256) void prep(const float* __restrict__ x,
                                            unsigned short* __restrict__ xo,
                                            unsigned int* __restrict__ xpadz,
                                            const float* __restrict__ w_in,
                                            const float* __restrict__ w_off,
                                            const float* __restrict__ w_mask,
                                            const float* __restrict__ w_out,
                                            unsigned short* __restrict__ wtin,
                                            unsigned short* __restrict__ wtoff,
                                            unsigned short* __restrict__ wtmsk,
                                            unsigned short* __restrict__ wtout,
                                            const float* __restrict__ b_off,
                                            const float* __restrict__ b_mask,
                                            float* __restrict__ bias_om,
                                            const float* __restrict__ dw_w,
                                            unsigned short* __restrict__ dwtb,
                                            unsigned int* __restrict__ bpad) {
    int z = blockIdx.z;
    int tx = threadIdx.x, ty = threadIdx.y;
    int t = ty * 32 + tx;
    if (z < 4) {
        // ring-only zero of group-planar xpad: 4n x 16g x 528 ring px x 8 uints = 270,336
        int flat = (z * 8 + blockIdx.y) * 128 + blockIdx.x;   // 0..4095
        unsigned int i = flat * 256 + t;                      // 0..1048575
        if (i < 270336u) {
            int o = i & 7;
            int rp = i >> 3;              // 0..33791
            int n = rp / 8448, rem = rp % 8448;
            int g = rem / 528, idx = rem % 528;
            int h, w;
            if (idx < 272) {
                static const int hr[4] = {0, 1, 66, 67};
                h = hr[idx / 68]; w = idx % 68;
            } else {
                int j = idx - 272;
                static const int wr[4] = {0, 1, 66, 67};
                h = 2 + (j >> 2); w = wr[j & 3];
            }
            xpadz[((size_t)(n * 16 + g) * PLANE + h * WP2 + w) * 8 + o] = 0u;
        }
        __shared__ float tt[32][33];
        int hw0 = blockIdx.x * 32, c0 = blockIdx.y * 32, n = z;
#pragma unroll
        for (int i2 = 0; i2 < 4; i2++)
            tt[ty + i2 * 8][tx] = x[(size_t)(n * CCH + c0 + ty + i2 * 8) * 4096 + hw0 + tx];
        __syncthreads();
#pragma unroll
        for (int i2 = 0; i2 < 4; i2++)
            xo[(size_t)(n * 4096 + hw0 + ty + i2 * 8) * CCH + c0 + tx] = f2bf(tt[tx][ty + i2 * 8]);
        return;
    }
    if (z == 8) {
        if (blockIdx.y == 0) {
            if (blockIdx.x < 2) {
                int i = blockIdx.x * 256 + t;
                if (i < 432) bias_om[i] = (i < 288) ? b_off[i] : b_mask[i - 288];
            } else if (blockIdx.x < 11) {
                int tap = blockIdx.x - 2;
                dwtb[tap * 256 + t] = f2bf(dw_w[t * 9 + tap]);
            } else if (blockIdx.x < 51) {
                bpad[(blockIdx.x - 11) * 256 + t] = 0u;   // 80 zero rows x 256 bf16
            }
        }
        return;
    }
    const float* w; unsigned short* wt; int N;
    if (z == 4)      { w = w_in;   wt = wtin;  N = 256; }
    else if (z == 5) { w = w_off;  wt = wtoff; N = 288; }
    else if (z == 6) { w = w_mask; wt = wtmsk; N = 144; }
    else             { w = w_out;  wt = wtout; N = 256; }
    const int K = 256;
    int n0 = blockIdx.x * 32, k0 = blockIdx.y * 32;
    if (n0 >= N) return;
    __shared__ float tb[32][33];
#pragma unroll
    for (int i = 0; i < 4; i++) {
        int k = k0 + ty + i * 8;
        if (n0 + tx < N) tb[ty + i * 8][tx] = w[(size_t)k * N + n0 + tx];
    }
    __syncthreads();
#pragma unroll
    for (int i = 0; i < 4; i++) {
        int n = n0 + ty + i * 8;
        if (n < N) wt[(size_t)n * K + k0 + tx] = f2bf(tb[tx][ty + i * 8]);
    }
}

// ---- LDS-staged 128x128 MFMA GEMM tile (m97 structure: BK=32, 2 barriers/k-step) ----
// MODE 1: bf16 scatter to GROUP-PLANAR padded xpad [n][g][68][68][16]
// MODE 4: f32 NCHW swapped (rows=channels, cols=pixels); Bt = y [m][256] rows
// MODE 5: packed control records [g][m][32 ushorts] (j<18 offsets, 18..26 mask logits)
template<int MODE>
__device__ __forceinline__ void gemm_tile(const unsigned short* __restrict__ A,
                                          const unsigned short* __restrict__ Bt,
                                          const float* __restrict__ bias,
                                          void* __restrict__ C0,
                                          int N, int K, int bm, int bn, int tid,
                                          unsigned short* As, unsigned short* Bs) {
    int wid = tid >> 6, lane = tid & 63;
    int wr = wid >> 1, wc = wid & 1;
    int lr = lane & 15, kg = lane >> 4;
    int r = lane >> 2, q = lane & 3;

    const unsigned short* Ag0 = A + (size_t)(bm + 32 * wid + r) * K + q * 8;
    const unsigned short* Ag1 = Ag0 + (size_t)16 * K;
    const unsigned short* Bg0 = Bt + (size_t)(bn + 32 * wid + r) * K + q * 8;
    const unsigned short* Bg1 = Bg0 + (size_t)16 * K;
    unsigned short* Al0 = As + wid * 1024;
    unsigned short* Al1 = Al0 + 512;
    unsigned short* Bl0 = Bs + wid * 1024;
    unsigned short* Bl1 = Bl0 + 512;

    const unsigned short* Ar = As + (wr * 64 + lr) * 32 + kg * 8;
    const unsigned short* Br = Bs + (wc * 64 + lr) * 32 + kg * 8;

    f32x4 acc[4][4];
#pragma unroll
    for (int i = 0; i < 4; i++)
#pragma unroll
        for (int j = 0; j < 4; j++) acc[i][j] = (f32x4){0.f, 0.f, 0.f, 0.f};

    for (int k0 = 0; k0 < K; k0 += 32) {
        gll16(Ag0 + k0, Al0);
        gll16(Ag1 + k0, Al1);
        gll16(Bg0 + k0, Bl0);
        gll16(Bg1 + k0, Bl1);
        __syncthreads();
        bf16x8 a[4], b[4];
#pragma unroll
        for (int i = 0; i < 4; i++) a[i] = *(const bf16x8*)(Ar + i * 512);
#pragma unroll
        for (int j = 0; j < 4; j++) b[j] = *(const bf16x8*)(Br + j * 512);
        __builtin_amdgcn_s_setprio(1);
#pragma unroll
        for (int i = 0; i < 4; i++)
#pragma unroll
            for (int j = 0; j < 4; j++)
                acc[i][j] = __builtin_amdgcn_mfma_f32_16x16x32_bf16(a[i], b[j], acc[i][j], 0, 0, 0);
        __builtin_amdgcn_s_setprio(0);
        __syncthreads();
    }

    int row0 = bm + wr * 64, col0 = bn + wc * 64;
#pragma unroll
    for (int i = 0; i < 4; i++) {
#pragma unroll
        for (int j = 0; j < 4; j++) {
            int col = col0 + j * 16 + lr;
            if (col >= N) continue;
            float bc = (MODE == 4) ? 0.f : bias[col];
#pragma unroll
            for (int r2 = 0; r2 < 4; r2++) {
                int m = row0 + i * 16 + kg * 4 + r2;
                float val = acc[i][j][r2] + bc;
                if (MODE == 1) {
                    int n = m >> 12, hw = m & 4095, h = hw >> 6, w = hw & 63;
                    int g = col >> 4, c = col & 15;
                    ((unsigned short*)C0)[((size_t)(n * 16 + g) * PLANE + (h + 2) * WP2 + (w + 2)) * 16 + c] = f2bf(val);
                } else if (MODE == 4) {
                    int n = col >> 12, hw = col & 4095;
                    ((float*)C0)[(size_t)(n * CCH + m) * 4096 + hw] = val + bias[m];
                } else {
                    int g, j2;
                    if (col < 288) { g = col / 18; j2 = col % 18; }
                    else { int cc = col - 288; g = cc / 9; j2 = 18 + cc % 9; }
                    ((unsigned short*)C0)[((size_t)g * NPIX + m) * 32 + j2] = f2bf(val);
                }
            }
        }
    }
}

template<int MODE>
__global__ __launch_bounds__(256) void gemm_mfma(const unsigned short* __restrict__ A,
                                                 const unsigned short* __restrict__ Bt,
                                                 const float* __restrict__ bias,
                                                 void* __restrict__ C0,
                                                 int N, int K) {
    __shared__ unsigned short As[4096];
    __shared__ unsigned short Bs[4096];
    gemm_tile<MODE>(A, Bt, bias, C0, N, K, blockIdx.y * 128, blockIdx.x * 128,
                    threadIdx.x, As, Bs);
}

// stage2: blocks [0,256) -> input_proj GEMM (mode 1); blocks [256,768) -> conv+LN+GELU.
// conv v4: wave = 8 pixels (two 4-pixel runs); lane owns 8 channels x 4-pixel run.
__global__ __launch_bounds__(256) void stage2(const unsigned short* __restrict__ xnbf,
                                              const unsigned short* __restrict__ wtin,
                                              const float* __restrict__ b_in,
                                              unsigned short* __restrict__ xpad,
                                              const unsigned short* __restrict__ dwtb,
                                              const float* __restrict__ dw_b,
                                              const float* __restrict__ ln_g,
                                              const float* __restrict__ ln_b,
                                              unsigned short* __restrict__ x1) {
    __shared__ unsigned short As[4096];
    __shared__ unsigned short Bs[4096];
    int bid = blockIdx.x;
    if (bid < 256) {
        gemm_tile<1>(xnbf, wtin, b_in, xpad, 256, 256,
                     (bid >> 1) * 128, (bid & 1) * 128, threadIdx.x, As, Bs);
        return;
    }
    int cb = bid - 256;                          // 0..511
    int sb = (cb & 7) * 64 + (cb >> 3);          // XCD chunk swizzle (512 % 8 == 0)
    int wid = threadIdx.x >> 6, lane = threadIdx.x & 63;
    int sub = lane >> 5, li = lane & 31;
    int mb = sb * 32 + wid * 8 + sub * 4;        // 4 consecutive pixels (aligned run)
    int n = mb >> 12, hw = mb & 4095, h = hw >> 6, w0 = hw & 63;   // w0 % 4 == 0
    int c0 = li << 3;

    float acc[4][8];
    {
        float4 b0 = *(const float4*)(dw_b + c0);
        float4 b1 = *(const float4*)(dw_b + c0 + 4);
        float bb[8] = {b0.x, b0.y, b0.z, b0.w, b1.x, b1.y, b1.z, b1.w};
#pragma unroll
        for (int j = 0; j < 4; j++)
#pragma unroll
            for (int q = 0; q < 8; q++) acc[j][q] = bb[q];
    }
    const u16x8 zz = {0, 0, 0, 0, 0, 0, 0, 0};
#pragma unroll
    for (int ky = 0; ky < 3; ky++) {
        int hy = h + ky - 1;
        if ((unsigned)hy >= 64u) continue;
        const unsigned short* rowp = xnbf + (size_t)(n * 4096 + hy * 64) * CCH + c0;
        u16x8 tap[6];
#pragma unroll
        for (int k6 = 0; k6 < 6; k6++) {
            int wx = w0 + k6 - 1;
            tap[k6] = ((unsigned)wx < 64u) ? *(const u16x8*)(rowp + (size_t)wx * CCH) : zz;
        }
        u16x8 wv[3];
#pragma unroll
        for (int kx = 0; kx < 3; kx++)
            wv[kx] = *(const u16x8*)(dwtb + (ky * 3 + kx) * CCH + c0);
#pragma unroll
        for (int j = 0; j < 4; j++)
#pragma unroll
            for (int kx = 0; kx < 3; kx++)
#pragma unroll
                for (int q = 0; q < 8; q++)
                    acc[j][q] += bf2f(tap[j + kx][q]) * bf2f(wv[kx][q]);
    }
    float s[4], s2[4];
#pragma unroll
    for (int j = 0; j < 4; j++) {
        s[j] = 0.f; s2[j] = 0.f;
#pragma unroll
        for (int q = 0; q < 8; q++) { s[j] += acc[j][q]; s2[j] += acc[j][q] * acc[j][q]; }
    }
#pragma unroll
    for (int off = 16; off; off >>= 1) {         // masks <32: stays within each 32-lane half
#pragma unroll
        for (int j = 0; j < 4; j++) {
            s[j] += __shfl_xor(s[j], off);
            s2[j] += __shfl_xor(s2[j], off);
        }
    }
    float4 g0 = *(const float4*)(ln_g + c0);
    float4 g1 = *(const float4*)(ln_g + c0 + 4);
    float4 bb0 = *(const float4*)(ln_b + c0);
    float4 bb1 = *(const float4*)(ln_b + c0 + 4);
    float gg[8] = {g0.x, g0.y, g0.z, g0.w, g1.x, g1.y, g1.z, g1.w};
    float bbv[8] = {bb0.x, bb0.y, bb0.z, bb0.w, bb1.x, bb1.y, bb1.z, bb1.w};
    const float is2 = 0.70710678118654752f;
#pragma unroll
    for (int j = 0; j < 4; j++) {
        float mean = s[j] * (1.f / 256.f);
        float var = s2[j] * (1.f / 256.f) - mean * mean;
        float rstd = 1.f / sqrtf(var + 1e-5f);
        u16x8 o;
#pragma unroll
        for (int q = 0; q < 8; q++) {
            float gv = (acc[j][q] - mean) * rstd * gg[q] + bbv[q];
            o[q] = f2bf(0.5f * gv * (1.f + erff(gv * is2)));
        }
        *(u16x8*)(x1 + (size_t)(mb + j) * CCH + c0) = o;
    }
}

// DCNv3 core + fused mask softmax; GROUP-PLANAR xpad, packed 64B control records [g][m][32].
// wave = 32 consecutive pixels x 1 group x 2 halves; 2048 blocks XCD-swizzled.
// y output standard [m][256].
__global__ __launch_bounds__(256) void dcn_core(const unsigned short* __restrict__ xpad,
                                                const unsigned short* __restrict__ recs,
                                                unsigned short* __restrict__ y) {
    int bid = blockIdx.x;
    int sb = (bid & 7) * 256 + (bid >> 3);
    int u = sb * 256 + threadIdx.x;          // 0 .. 524287
    int half = u & 1;
    int w32 = (u >> 1) & 31;
    int rest = u >> 6;
    int g = rest & 15;
    int mb = rest >> 4;
    int m = mb * 32 + w32;
    int n = m >> 12, hw = m & 4095, h = hw >> 6, w = hw & 63;

    const unsigned short* rec = recs + ((size_t)g * NPIX + m) * 32;
    u16x8 L0 = *(const u16x8*)(rec);
    u16x8 L1 = *(const u16x8*)(rec + 8);
    u16x8 L2 = *(const u16x8*)(rec + 16);
    u16x8 L3 = *(const u16x8*)(rec + 24);
    unsigned short ctl[27];
#pragma unroll
    for (int e = 0; e < 8; e++) { ctl[e] = L0[e]; ctl[8 + e] = L1[e]; ctl[16 + e] = L2[e]; }
    ctl[24] = L3[0]; ctl[25] = L3[1]; ctl[26] = L3[2];

    float mv[9];
    float mx = -1e30f;
#pragma unroll
    for (int i = 0; i < 9; i++) { mv[i] = bf2f(ctl[18 + i]); mx = fmaxf(mx, mv[i]); }
    float s = 0.f;
#pragma unroll
    for (int i = 0; i < 9; i++) { mv[i] = expf(mv[i] - mx); s += mv[i]; }
    float rs = 1.f / s;

    const unsigned short* xb = xpad + (size_t)(n * 16 + g) * (PLANE * 16) + half * 8;

    float acc[8] = {0.f};
#pragma unroll
    for (int p = 0; p < 9; p++) {
        int dx = p / 3 - 1, dy = p % 3 - 1;
        float ox = bf2f(ctl[2 * p]);
        float oy = bf2f(ctl[2 * p + 1]);
        // pixel center in 68x68 coords; clamp is EXACT vs reference masking
        float px = fminf(fmaxf((float)(w + 2 + dx) + ox, 0.f), 67.f);
        float py = fminf(fmaxf((float)(h + 2 + dy) + oy, 0.f), 67.f);
        float x0f = floorf(px), y0f = floorf(py);
        float fx = px - x0f, fy = py - y0f;
        int x0 = (int)x0f, y0 = (int)y0f;
        int y1c = min(y0 + 1, 67);
        float mval = mv[p] * rs;
        float w00 = (1.f - fx) * (1.f - fy) * mval;
        float w01 = fx * (1.f - fy) * mval;
        float w10 = (1.f - fx) * fy * mval;
        float w11 = fx * fy * mval;
        const unsigned short* r0 = xb + ((size_t)y0 * WP2 + x0) * 16;
        const unsigned short* r1 = xb + ((size_t)y1c * WP2 + x0) * 16;
        // x0+1 record is +16 elems; when x0==67 its weight is exactly 0 (fx==0) and the
        // 32B spill lands in the next plane / following ws buffer - harmless.
        u16x8 v00 = *(const u16x8*)(r0);
        u16x8 v01 = *(const u16x8*)(r0 + 16);
        u16x8 v10 = *(const u16x8*)(r1);
        u16x8 v11 = *(const u16x8*)(r1 + 16);
#pragma unroll
        for (int q = 0; q < 8; q++)
            acc[q] += w00 * bf2f(v00[q]) + w01 * bf2f(v01[q])
                    + w10 * bf2f(v10[q]) + w11 * bf2f(v11[q]);
    }
    u16x8 v;
#pragma unroll
    for (int q = 0; q < 8; q++) v[q] = f2bf(acc[q]);
    *(u16x8*)(y + (size_t)m * CCH + g * 16 + half * 8) = v;
}

extern "C" void kernel_launch(void* const* d_in, const int* in_sizes, int n_in,
                              void* d_out, int out_size, void* d_ws, size_t ws_size,
                              hipStream_t stream) {
    const float* x      = (const float*)d_in[0];
    const float* w_in   = (const float*)d_in[1];
    const float* b_in   = (const float*)d_in[2];
    const float* dw_w   = (const float*)d_in[3];
    const float* dw_b   = (const float*)d_in[4];
    const float* ln_g   = (const float*)d_in[5];
    const float* ln_b   = (const float*)d_in[6];
    const float* w_off  = (const float*)d_in[7];
    const float* b_off  = (const float*)d_in[8];
    const float* w_mask = (const float*)d_in[9];
    const float* b_mask = (const float*)d_in[10];
    const float* w_out  = (const float*)d_in[11];
    const float* b_out  = (const float*)d_in[12];
    float* out = (float*)d_out;
    char* ws = (char*)d_ws;

    unsigned short* xnbf  = (unsigned short*)(ws + OFF_XNBF);
    unsigned short* xpad  = (unsigned short*)(ws + OFF_XPAD);
    unsigned short* x1bf  = (unsigned short*)(ws + OFF_X1BF);
    unsigned short* recs  = (unsigned short*)(ws + OFF_REC);
    unsigned short* wtin  = (unsigned short*)(ws + OFF_WTIN);
    unsigned short* wtoff = (unsigned short*)(ws + OFF_WTOFF);
    unsigned short* wtmsk = (unsigned short*)(ws + OFF_WTMSK);
    unsigned int*   bpad  = (unsigned int*)(ws + OFF_BPAD);
    unsigned short* wtout = (unsigned short*)(ws + OFF_WTOUT);
    float*          biasom = (float*)(ws + OFF_BOM);
    unsigned short* dwtb  = (unsigned short*)(ws + OFF_DWT);
    unsigned short* ybf   = xnbf;   // xnbf dead after stage2; y standard [m][256]

    // 1. fused prep: NCHW->NHWC bf16 + xpad ring-zero + weight transposes + biases + B-pad zero
    prep<<<dim3(128, 8, 9), dim3(32, 8), 0, stream>>>(x, xnbf, (unsigned int*)xpad,
                                                      w_in, w_off, w_mask, w_out,
                                                      wtin, wtoff, wtmsk, wtout,
                                                      b_off, b_mask, biasom, dw_w, dwtb, bpad);
    // 2. fused: input_proj GEMM (256 blocks, group-planar epilogue) || conv v4 (512 blocks)
    stage2<<<768, 256, 0, stream>>>(xnbf, wtin, b_in, xpad, dwtb, dw_b, ln_g, ln_b, x1bf);
    // 3. fused offset+mask GEMM -> packed 64B control records [g][m][32]
    gemm_mfma<5><<<dim3(4, 128), 256, 0, stream>>>(x1bf, wtoff, biasom, recs, 432, 256);
    // 4. DCNv3 core + fused softmax (group-planar gathers, packed control, XCD-swizzled)
    dcn_core<<<2048, 256, 0, stream>>>(xpad, recs, ybf);
    // 5. output_proj GEMM, swapped (rows=channels) -> coalesced NCHW f32; Bt = y [m][256]
    gemm_mfma<4><<<dim3(128, 2), 256, 0, stream>>>(wtout, ybf, b_out, out, 16384, 256);
}

// Round 14
// 77.152 us; speedup vs baseline: 1.0227x; 1.0227x over previous
//
#include <hip/hip_runtime.h>
#include <math.h>

#define CCH 256
#define HP2 68
#define WP2 68
#define NPIX 16384

typedef __attribute__((ext_vector_type(8))) short bf16x8;
typedef __attribute__((ext_vector_type(8))) unsigned short u16x8;
typedef __attribute__((ext_vector_type(4))) float f32x4;

__device__ __forceinline__ unsigned short f2bf(float f) {
    unsigned int u = __float_as_uint(f);
    unsigned int r = (u + 0x7fffu + ((u >> 16) & 1u)) >> 16;
    return (unsigned short)r;
}
__device__ __forceinline__ float bf2f(unsigned short h) {
    return __uint_as_float(((unsigned int)h) << 16);
}

// async global->LDS, 16B per lane; LDS dest is wave-uniform base + lane*16
__device__ __forceinline__ void gll16(const unsigned short* g, unsigned short* l) {
    __builtin_amdgcn_global_load_lds(
        (const __attribute__((address_space(1))) unsigned int*)g,
        (__attribute__((address_space(3))) unsigned int*)l,
        16, 0, 0);
}

// ---- workspace layout (bytes) ----
#define OFF_XNBF   0ull          // 16384*256 bf16 = 8,388,608  (reused as y_bf after stage2)
#define OFF_XPAD   8388608ull    // 4*68*68*256 bf16 = 9,469,952 (only border ring re-zeroed)
#define OFF_X1BF   17858560ull   // 16384*256 bf16 = 8,388,608
#define OFF_OFFS   26247168ull   // 16384*288 bf16 = 9,437,184
#define OFF_MASK   35684352ull   // 16384*144 bf16 = 4,718,592
#define OFF_WTIN   40402944ull   // 256*256 bf16   = 131,072
#define OFF_WTOFF  40534016ull   // 288*256 bf16   = 147,456   (wtoff+wtmsk+pad contiguous = 512xK)
#define OFF_WTMSK  40681472ull   // 144*256 bf16   = 73,728
#define OFF_BPAD   40755200ull   // 80*256 bf16    = 40,960   (zero pad rows 432..511)
#define OFF_WTOUT  40796160ull   // 256*256 bf16   = 131,072
#define OFF_BOM    40927232ull   // 432 f32        = 1,728
#define OFF_DWT    40928960ull   // 9*256 bf16     = 4,608  (depthwise w, tap-major)
// end = 40,933,568 bytes

// prep (minimal critical path): z<4 -> NCHW f32 -> NHWC bf16 (+ ring-zero xpad);
// z=4 -> wtin transpose; z=5 -> dwtb (tap-major depthwise weights)
__global__ __launch_bounds__(256) void prep(const float* __restrict__ x,
                                            unsigned short* __restrict__ xo,
                                            unsigned int* __restrict__ xpadz,
                                            const float* __restrict__ w_in,
                                            unsigned short* __restrict__ wtin,
                                            const float* __restrict__ dw_w,
                                            unsigned short* __restrict__ dwtb) {
    int z = blockIdx.z;
    int tx = threadIdx.x, ty = threadIdx.y;
    int t = ty * 32 + tx;
    if (z < 4) {
        // ring-only zero of xpad: 2112 border pixels x 128 uints = 270,336 uints
        int flat = (z * 8 + blockIdx.y) * 128 + blockIdx.x;   // 0..4095
        unsigned int i = flat * 256 + t;                      // 0..1048575
        if (i < 270336u) {
            int rp = i >> 7, o = i & 127;
            int n = rp / 528, idx = rp % 528;
            int h, w;
            if (idx < 272) {
                static const int hr[4] = {0, 1, 66, 67};
                h = hr[idx / 68]; w = idx % 68;
            } else {
                int j = idx - 272;
                static const int wr[4] = {0, 1, 66, 67};
                h = 2 + (j >> 2); w = wr[j & 3];
            }
            xpadz[(size_t)(n * (HP2 * WP2) + h * WP2 + w) * 128 + o] = 0u;
        }
        __shared__ float tt[32][33];
        int hw0 = blockIdx.x * 32, c0 = blockIdx.y * 32, n = z;
#pragma unroll
        for (int i2 = 0; i2 < 4; i2++)
            tt[ty + i2 * 8][tx] = x[(size_t)(n * CCH + c0 + ty + i2 * 8) * 4096 + hw0 + tx];
        __syncthreads();
#pragma unroll
        for (int i2 = 0; i2 < 4; i2++)
            xo[(size_t)(n * 4096 + hw0 + ty + i2 * 8) * CCH + c0 + tx] = f2bf(tt[tx][ty + i2 * 8]);
        return;
    }
    if (z == 4) {
        if (blockIdx.x >= 8) return;
        const int K = 256, N = 256;
        int n0 = blockIdx.x * 32, k0 = blockIdx.y * 32;
        __shared__ float tb[32][33];
#pragma unroll
        for (int i = 0; i < 4; i++)
            tb[ty + i * 8][tx] = w_in[(size_t)(k0 + ty + i * 8) * N + n0 + tx];
        __syncthreads();
#pragma unroll
        for (int i = 0; i < 4; i++)
            wtin[(size_t)(n0 + ty + i * 8) * K + k0 + tx] = f2bf(tb[tx][ty + i * 8]);
        return;
    }
    // z == 5: dwtb
    if (blockIdx.y == 0 && blockIdx.x < 9) {
        int tap = blockIdx.x;
        dwtb[tap * 256 + t] = f2bf(dw_w[t * 9 + tap]);
    }
}

// ---- LDS-staged 128x128 MFMA GEMM tile (m97 structure: BK=32, 2 barriers/k-step) ----
// MODE 1: bf16 scatter to padded 68x68 NHWC; MODE 4: f32 NCHW swapped (rows=channels);
// MODE 5: dual bf16 row-major (col<288 -> C0 ld288, else C1 ld144)
template<int MODE>
__device__ __forceinline__ void gemm_tile(const unsigned short* __restrict__ A,
                                          const unsigned short* __restrict__ Bt,
                                          const float* __restrict__ bias,
                                          void* __restrict__ C0, void* __restrict__ C1,
                                          int N, int K, int bm, int bn, int tid,
                                          unsigned short* As, unsigned short* Bs) {
    int wid = tid >> 6, lane = tid & 63;
    int wr = wid >> 1, wc = wid & 1;
    int lr = lane & 15, kg = lane >> 4;
    int r = lane >> 2, q = lane & 3;

    const unsigned short* Ag0 = A + (size_t)(bm + 32 * wid + r) * K + q * 8;
    const unsigned short* Ag1 = Ag0 + (size_t)16 * K;
    const unsigned short* Bg0 = Bt + (size_t)(bn + 32 * wid + r) * K + q * 8;
    const unsigned short* Bg1 = Bg0 + (size_t)16 * K;
    unsigned short* Al0 = As + wid * 1024;
    unsigned short* Al1 = Al0 + 512;
    unsigned short* Bl0 = Bs + wid * 1024;
    unsigned short* Bl1 = Bl0 + 512;

    const unsigned short* Ar = As + (wr * 64 + lr) * 32 + kg * 8;
    const unsigned short* Br = Bs + (wc * 64 + lr) * 32 + kg * 8;

    f32x4 acc[4][4];
#pragma unroll
    for (int i = 0; i < 4; i++)
#pragma unroll
        for (int j = 0; j < 4; j++) acc[i][j] = (f32x4){0.f, 0.f, 0.f, 0.f};

    for (int k0 = 0; k0 < K; k0 += 32) {
        gll16(Ag0 + k0, Al0);
        gll16(Ag1 + k0, Al1);
        gll16(Bg0 + k0, Bl0);
        gll16(Bg1 + k0, Bl1);
        __syncthreads();
        bf16x8 a[4], b[4];
#pragma unroll
        for (int i = 0; i < 4; i++) a[i] = *(const bf16x8*)(Ar + i * 512);
#pragma unroll
        for (int j = 0; j < 4; j++) b[j] = *(const bf16x8*)(Br + j * 512);
        __builtin_amdgcn_s_setprio(1);
#pragma unroll
        for (int i = 0; i < 4; i++)
#pragma unroll
            for (int j = 0; j < 4; j++)
                acc[i][j] = __builtin_amdgcn_mfma_f32_16x16x32_bf16(a[i], b[j], acc[i][j], 0, 0, 0);
        __builtin_amdgcn_s_setprio(0);
        __syncthreads();
    }

    int row0 = bm + wr * 64, col0 = bn + wc * 64;
#pragma unroll
    for (int i = 0; i < 4; i++) {
#pragma unroll
        for (int j = 0; j < 4; j++) {
            int col = col0 + j * 16 + lr;
            if (col >= N) continue;
            float bc = (MODE == 4) ? 0.f : bias[col];
#pragma unroll
            for (int r2 = 0; r2 < 4; r2++) {
                int m = row0 + i * 16 + kg * 4 + r2;
                float val = acc[i][j][r2] + bc;
                if (MODE == 1) {
                    int n = m >> 12, hw = m & 4095, h = hw >> 6, w = hw & 63;
                    ((unsigned short*)C0)[(size_t)((n * HP2 + h + 2) * WP2 + (w + 2)) * CCH + col] = f2bf(val);
                } else if (MODE == 4) {
                    int n = col >> 12, hw = col & 4095;
                    ((float*)C0)[(size_t)(n * CCH + m) * 4096 + hw] = val + bias[m];
                } else {
                    if (col < 288)
                        ((unsigned short*)C0)[(size_t)m * 288 + col] = f2bf(val);
                    else
                        ((unsigned short*)C1)[(size_t)m * 144 + (col - 288)] = f2bf(val);
                }
            }
        }
    }
}

template<int MODE>
__global__ __launch_bounds__(256) void gemm_mfma(const unsigned short* __restrict__ A,
                                                 const unsigned short* __restrict__ Bt,
                                                 const float* __restrict__ bias,
                                                 void* __restrict__ C0,
                                                 void* __restrict__ C1,
                                                 int N, int K) {
    __shared__ unsigned short As[4096];
    __shared__ unsigned short Bs[4096];
    gemm_tile<MODE>(A, Bt, bias, C0, C1, N, K, blockIdx.y * 128, blockIdx.x * 128,
                    threadIdx.x, As, Bs);
}

// stage2: [0,256) input_proj GEMM; [256,768) conv+LN+GELU;
// [768,986) deferred prep work (wtoff/wtmsk/wtout transposes, biasom, bpad) —
// consumed only by LATER dispatches, so producing it inside this dispatch is safe.
__global__ __launch_bounds__(256) void stage2(const unsigned short* __restrict__ xnbf,
                                              const unsigned short* __restrict__ wtin,
                                              const float* __restrict__ b_in,
                                              unsigned short* __restrict__ xpad,
                                              const unsigned short* __restrict__ dwtb,
                                              const float* __restrict__ dw_b,
                                              const float* __restrict__ ln_g,
                                              const float* __restrict__ ln_b,
                                              unsigned short* __restrict__ x1,
                                              const float* __restrict__ w_off,
                                              const float* __restrict__ w_mask,
                                              const float* __restrict__ w_out,
                                              unsigned short* __restrict__ wtoff,
                                              unsigned short* __restrict__ wtmsk,
                                              unsigned short* __restrict__ wtout,
                                              const float* __restrict__ b_off,
                                              const float* __restrict__ b_mask,
                                              float* __restrict__ biasom,
                                              unsigned int* __restrict__ bpad) {
    __shared__ unsigned short As[4096];
    __shared__ unsigned short Bs[4096];
    int bid = blockIdx.x;
    if (bid < 256) {
        gemm_tile<1>(xnbf, wtin, b_in, xpad, nullptr, 256, 256,
                     (bid >> 1) * 128, (bid & 1) * 128, threadIdx.x, As, Bs);
        return;
    }
    if (bid < 768) {
        int cb = bid - 256;                          // 0..511
        int sb = (cb & 7) * 64 + (cb >> 3);          // XCD chunk swizzle (512 % 8 == 0)
        int wid = threadIdx.x >> 6, lane = threadIdx.x & 63;
        int sub = lane >> 5, li = lane & 31;
        int mb = sb * 32 + wid * 8 + sub * 4;        // 4 consecutive pixels (aligned run)
        int n = mb >> 12, hw = mb & 4095, h = hw >> 6, w0 = hw & 63;   // w0 % 4 == 0
        int c0 = li << 3;

        float acc[4][8];
        {
            float4 b0 = *(const float4*)(dw_b + c0);
            float4 b1 = *(const float4*)(dw_b + c0 + 4);
            float bb[8] = {b0.x, b0.y, b0.z, b0.w, b1.x, b1.y, b1.z, b1.w};
#pragma unroll
            for (int j = 0; j < 4; j++)
#pragma unroll
                for (int q = 0; q < 8; q++) acc[j][q] = bb[q];
        }
        const u16x8 zz = {0, 0, 0, 0, 0, 0, 0, 0};
#pragma unroll
        for (int ky = 0; ky < 3; ky++) {
            int hy = h + ky - 1;
            if ((unsigned)hy >= 64u) continue;
            const unsigned short* rowp = xnbf + (size_t)(n * 4096 + hy * 64) * CCH + c0;
            u16x8 tap[6];
#pragma unroll
            for (int k6 = 0; k6 < 6; k6++) {
                int wx = w0 + k6 - 1;
                tap[k6] = ((unsigned)wx < 64u) ? *(const u16x8*)(rowp + (size_t)wx * CCH) : zz;
            }
            u16x8 wv[3];
#pragma unroll
            for (int kx = 0; kx < 3; kx++)
                wv[kx] = *(const u16x8*)(dwtb + (ky * 3 + kx) * CCH + c0);
#pragma unroll
            for (int j = 0; j < 4; j++)
#pragma unroll
                for (int kx = 0; kx < 3; kx++)
#pragma unroll
                    for (int q = 0; q < 8; q++)
                        acc[j][q] += bf2f(tap[j + kx][q]) * bf2f(wv[kx][q]);
        }
        float s[4], s2[4];
#pragma unroll
        for (int j = 0; j < 4; j++) {
            s[j] = 0.f; s2[j] = 0.f;
#pragma unroll
            for (int q = 0; q < 8; q++) { s[j] += acc[j][q]; s2[j] += acc[j][q] * acc[j][q]; }
        }
#pragma unroll
        for (int off = 16; off; off >>= 1) {         // masks <32: stays within each 32-lane half
#pragma unroll
            for (int j = 0; j < 4; j++) {
                s[j] += __shfl_xor(s[j], off);
                s2[j] += __shfl_xor(s2[j], off);
            }
        }
        float4 g0 = *(const float4*)(ln_g + c0);
        float4 g1 = *(const float4*)(ln_g + c0 + 4);
        float4 bb0 = *(const float4*)(ln_b + c0);
        float4 bb1 = *(const float4*)(ln_b + c0 + 4);
        float gg[8] = {g0.x, g0.y, g0.z, g0.w, g1.x, g1.y, g1.z, g1.w};
        float bbv[8] = {bb0.x, bb0.y, bb0.z, bb0.w, bb1.x, bb1.y, bb1.z, bb1.w};
        const float is2 = 0.70710678118654752f;
#pragma unroll
        for (int j = 0; j < 4; j++) {
            float mean = s[j] * (1.f / 256.f);
            float var = s2[j] * (1.f / 256.f) - mean * mean;
            float rstd = 1.f / sqrtf(var + 1e-5f);
            u16x8 o;
#pragma unroll
            for (int q = 0; q < 8; q++) {
                float gv = (acc[j][q] - mean) * rstd * gg[q] + bbv[q];
                o[q] = f2bf(0.5f * gv * (1.f + erff(gv * is2)));
            }
            *(u16x8*)(x1 + (size_t)(mb + j) * CCH + c0) = o;
        }
        return;
    }
    // deferred prep work
    int b = bid - 768;
    int t = threadIdx.x;
    int tx = t & 31, ty = t >> 5;
    if (b < 176) {
        const float* w; unsigned short* wt; int N, nb, idx;
        if (b < 72)       { w = w_off;  wt = wtoff; N = 288; nb = 9; idx = b; }
        else if (b < 112) { w = w_mask; wt = wtmsk; N = 144; nb = 5; idx = b - 72; }
        else              { w = w_out;  wt = wtout; N = 256; nb = 8; idx = b - 112; }
        const int K = 256;
        int n0 = (idx % nb) * 32, k0 = (idx / nb) * 32;
        float* tb = (float*)As;   // reuse GEMM LDS as 32x33 f32 scratch (4224 B <= 8192)
#pragma unroll
        for (int i = 0; i < 4; i++) {
            int k = k0 + ty + i * 8;
            if (n0 + tx < N) tb[(ty + i * 8) * 33 + tx] = w[(size_t)k * N + n0 + tx];
        }
        __syncthreads();
#pragma unroll
        for (int i = 0; i < 4; i++) {
            int n = n0 + ty + i * 8;
            if (n < N) wt[(size_t)n * K + k0 + tx] = f2bf(tb[tx * 33 + ty + i * 8]);
        }
    } else if (b < 178) {
        int i = (b - 176) * 256 + t;
        if (i < 432) biasom[i] = (i < 288) ? b_off[i] : b_mask[i - 288];
    } else {
        bpad[(size_t)(b - 178) * 256 + t] = 0u;   // 40 blocks x 256 = 10240 uints
    }
}

// DCNv3 core + fused mask softmax, branchless via 2-ring pad + coord clamp.
// one thread per (pixel, group, channel-half); 2048 blocks XCD-swizzled
__global__ __launch_bounds__(256) void dcn_core(const unsigned short* __restrict__ xpad,
                                                const unsigned short* __restrict__ offs,
                                                const unsigned short* __restrict__ mk,
                                                unsigned short* __restrict__ y) {
    int bid = blockIdx.x;
    int sb = (bid & 7) * 256 + (bid >> 3);
    int t = sb * 256 + threadIdx.x;          // 0 .. 524287
    int half = t & 1, g = (t >> 1) & 15, m = t >> 5;
    int n = m >> 12, hw = m & 4095, h = hw >> 6, w = hw & 63;
    const unsigned int* op32 = (const unsigned int*)(offs + (size_t)m * 288 + g * 18);
    const unsigned short* mp = mk + ((size_t)m * 16 + g) * 9;
    const unsigned short* xb = xpad + (size_t)n * (HP2 * WP2 * CCH) + g * 16 + half * 8;

    float mv[9];
    float mx = -1e30f;
#pragma unroll
    for (int i = 0; i < 9; i++) { mv[i] = bf2f(mp[i]); mx = fmaxf(mx, mv[i]); }
    float s = 0.f;
#pragma unroll
    for (int i = 0; i < 9; i++) { mv[i] = expf(mv[i] - mx); s += mv[i]; }
    float rs = 1.f / s;

    float acc[8] = {0.f};
#pragma unroll
    for (int p = 0; p < 9; p++) {
        int dx = p / 3 - 1, dy = p % 3 - 1;
        unsigned int pk = op32[p];
        float ox = bf2f((unsigned short)(pk & 0xffffu));
        float oy = bf2f((unsigned short)(pk >> 16));
        float px = fminf(fmaxf((float)(w + 2 + dx) + ox, 0.f), 67.f);
        float py = fminf(fmaxf((float)(h + 2 + dy) + oy, 0.f), 67.f);
        float x0f = floorf(px), y0f = floorf(py);
        float fx = px - x0f, fy = py - y0f;
        int x0 = (int)x0f, y0 = (int)y0f;
        int x1c = min(x0 + 1, 67), y1c = min(y0 + 1, 67);
        float mval = mv[p] * rs;
        float w00 = (1.f - fx) * (1.f - fy) * mval;
        float w01 = fx * (1.f - fy) * mval;
        float w10 = (1.f - fx) * fy * mval;
        float w11 = fx * fy * mval;
        const unsigned short* r0 = xb + (size_t)y0 * (WP2 * CCH);
        const unsigned short* r1 = xb + (size_t)y1c * (WP2 * CCH);
        u16x8 v00 = *(const u16x8*)(r0 + x0 * CCH);
        u16x8 v01 = *(const u16x8*)(r0 + x1c * CCH);
        u16x8 v10 = *(const u16x8*)(r1 + x0 * CCH);
        u16x8 v11 = *(const u16x8*)(r1 + x1c * CCH);
#pragma unroll
        for (int q = 0; q < 8; q++)
            acc[q] += w00 * bf2f(v00[q]) + w01 * bf2f(v01[q])
                    + w10 * bf2f(v10[q]) + w11 * bf2f(v11[q]);
    }
    u16x8 v;
#pragma unroll
    for (int q = 0; q < 8; q++) v[q] = f2bf(acc[q]);
    *(u16x8*)(y + (size_t)m * CCH + g * 16 + half * 8) = v;
}

extern "C" void kernel_launch(void* const* d_in, const int* in_sizes, int n_in,
                              void* d_out, int out_size, void* d_ws, size_t ws_size,
                              hipStream_t stream) {
    const float* x      = (const float*)d_in[0];
    const float* w_in   = (const float*)d_in[1];
    const float* b_in   = (const float*)d_in[2];
    const float* dw_w   = (const float*)d_in[3];
    const float* dw_b   = (const float*)d_in[4];
    const float* ln_g   = (const float*)d_in[5];
    const float* ln_b   = (const float*)d_in[6];
    const float* w_off  = (const float*)d_in[7];
    const float* b_off  = (const float*)d_in[8];
    const float* w_mask = (const float*)d_in[9];
    const float* b_mask = (const float*)d_in[10];
    const float* w_out  = (const float*)d_in[11];
    const float* b_out  = (const float*)d_in[12];
    float* out = (float*)d_out;
    char* ws = (char*)d_ws;

    unsigned short* xnbf  = (unsigned short*)(ws + OFF_XNBF);
    unsigned short* xpad  = (unsigned short*)(ws + OFF_XPAD);
    unsigned short* x1bf  = (unsigned short*)(ws + OFF_X1BF);
    unsigned short* offs  = (unsigned short*)(ws + OFF_OFFS);
    unsigned short* mkb   = (unsigned short*)(ws + OFF_MASK);
    unsigned short* wtin  = (unsigned short*)(ws + OFF_WTIN);
    unsigned short* wtoff = (unsigned short*)(ws + OFF_WTOFF);
    unsigned short* wtmsk = (unsigned short*)(ws + OFF_WTMSK);
    unsigned int*   bpad  = (unsigned int*)(ws + OFF_BPAD);
    unsigned short* wtout = (unsigned short*)(ws + OFF_WTOUT);
    float*          biasom = (float*)(ws + OFF_BOM);
    unsigned short* dwtb  = (unsigned short*)(ws + OFF_DWT);
    unsigned short* ybf   = xnbf;   // xnbf dead after stage2

    // 1. minimal prep: transpose + ring-zero + wtin + dwtb (only what stage2 needs)
    prep<<<dim3(128, 8, 6), dim3(32, 8), 0, stream>>>(x, xnbf, (unsigned int*)xpad,
                                                      w_in, wtin, dw_w, dwtb);
    // 2. fused: input_proj GEMM (256) || conv v4 (512) || deferred prep (218)
    stage2<<<986, 256, 0, stream>>>(xnbf, wtin, b_in, xpad, dwtb, dw_b, ln_g, ln_b, x1bf,
                                    w_off, w_mask, w_out, wtoff, wtmsk, wtout,
                                    b_off, b_mask, biasom, bpad);
    // 3. fused offset+mask GEMM (N=432, B padded to 512 rows, dual bf16 out)
    gemm_mfma<5><<<dim3(4, 128), 256, 0, stream>>>(x1bf, wtoff, biasom, offs, mkb, 432, 256);
    // 4. DCNv3 core + fused softmax (branchless, XCD-swizzled)
    dcn_core<<<2048, 256, 0, stream>>>(xpad, offs, mkb, ybf);
    // 5. output_proj GEMM, swapped (rows=channels) -> coalesced NCHW f32
    gemm_mfma<4><<<dim3(128, 2), 256, 0, stream>>>(wtout, ybf, b_out, out, nullptr, 16384, 256);
}